// Round 10
// baseline (77.844 us; speedup 1.0000x reference)
//
#include <hip/hip_runtime.h>
#include <hip/hip_fp16.h>
#include <math.h>

#define NV 10475
#define NDS 2048
#define NHAND 1554
#define NHA 777
#define NCONTACT 300
#define NQ (NHAND + NDS)             // 3602 query rows
#define NVEC4 (NV / 4)               // 2618 float4 per row
#define TAIL0 (NVEC4 * 4)            // 10472
#define MASK_DW ((NV + 31) / 32)     // 328

#define PREP_BLOCKS 41               // 41*256 >= NV
#define LIGHT_BLOCKS 15              // 15*256 >= NQ
#define K1_BLOCKS (PREP_BLOCKS + LIGHT_BLOCKS)    // 56

#define GDI_BLOCKS 41
#define HEAVY_BLOCKS 135
#define K2_BLOCKS (GDI_BLOCKS + HEAVY_BLOCKS)     // 176
#define HEAVY_WAVES (HEAVY_BLOCKS * 4)            // 540 waves (~= expected heavy count)

#define GEO_THRESH 0.3f
#define EXT_THRESH 0.02f
#define A1c 0.04f
#define A2c 0.04f
#define B1c 0.07f
#define B2c 0.06f
#define C1c 0.01f
#define C2c 0.01f
#define D1c 0.023f
#define D2c 0.02f
#define CONTACT_W 0.5f
#define INSIDE_W 0.5f
#define HAND_W 1.0f

__device__ __forceinline__ void upd(float g, float cx, float cy, float cz,
                                    float px, float py, float pz, float& best) {
    float dx = px - cx, dy = py - cy, dz = pz - cz;
    float d2 = fmaf(dx, dx, fmaf(dy, dy, dz * dz));
    best = fminf(best, (g < GEO_THRESH) ? INFINITY : d2);
}

// ---------------------------------------------------------------------------
// K1: blocks [0,41): fp16-round vertices -> global SoA float arrays.
//     blocks [41,56): per-query self check. Diagonal geodist[q][q] >= 0.3
//     means the self-pair (d2 == 0, the global min of d2) is UNMASKED ->
//     answer is sqrt(0 + 1e-12) immediately. Else enqueue as heavy.
// ---------------------------------------------------------------------------
__global__ void prep_light_kernel(const float* __restrict__ verts,
                                  const float* __restrict__ geodist,
                                  const int* __restrict__ hand_idx,
                                  const int* __restrict__ ds,
                                  float* __restrict__ vx,
                                  float* __restrict__ vy,
                                  float* __restrict__ vz,
                                  float* __restrict__ hand_min,
                                  float* __restrict__ ds_min,
                                  int* __restrict__ heavy_cnt,
                                  int* __restrict__ heavy) {
    const int tid = threadIdx.x;
    if (blockIdx.x < PREP_BLOCKS) {
        const int n = blockIdx.x * 256 + tid;
        if (n < NV) {
            vx[n] = __half2float(__float2half(verts[3 * n + 0]));
            vy[n] = __half2float(__float2half(verts[3 * n + 1]));
            vz[n] = __half2float(__float2half(verts[3 * n + 2]));
        }
        return;
    }
    const int t = (blockIdx.x - PREP_BLOCKS) * 256 + tid;
    if (t >= NQ) return;
    const bool is_ds = (t >= NHAND);
    const int i_out = is_ds ? (t - NHAND) : t;
    const int q = is_ds ? ds[i_out] : hand_idx[t];
    const float gqq = geodist[(size_t)q * NV + q];
    if (gqq >= GEO_THRESH) {
        const float d = sqrtf(0.0f + 1e-12f);   // identical expression to scan path
        if (is_ds) ds_min[i_out] = d; else hand_min[t] = d;
    } else {
        const int slot = atomicAdd(heavy_cnt, 1);
        heavy[slot] = t;
    }
}

// ---------------------------------------------------------------------------
// K2: blocks [0,41): gdi column stripes -- pgdi[v] = min_j geodist[cidx[j], v]
//     (== min_j geodist[v, cidx[j]] by exact symmetry of 0.5*(g+g^T)).
//     blocks [41,176): one wave per heavy query (grid-stride): R5's proven
//     masked float4 row scan, coords from L2-resident global SoA arrays.
//     Self-pair needs no special case: heavy implies geodist[q][q] < 0.3, so
//     the same mask test kills the d2=0 self candidate.
// ---------------------------------------------------------------------------
__global__ void gdi_heavy_kernel(const float* __restrict__ geodist,
                                 const float* __restrict__ vx,
                                 const float* __restrict__ vy,
                                 const float* __restrict__ vz,
                                 const int* __restrict__ hand_idx,
                                 const int* __restrict__ ds,
                                 const int* __restrict__ cidx,
                                 const int* __restrict__ heavy_cnt,
                                 const int* __restrict__ heavy,
                                 float* __restrict__ hand_min,
                                 float* __restrict__ ds_min,
                                 float* __restrict__ pgdi) {
    const int tid = threadIdx.x;
    if (blockIdx.x < GDI_BLOCKS) {
        const int v = blockIdx.x * 256 + tid;
        if (v < NV) {
            float m = INFINITY;
            #pragma unroll 4
            for (int j = 0; j < NCONTACT; ++j)
                m = fminf(m, geodist[(size_t)cidx[j] * NV + v]);
            pgdi[v] = m;
        }
        return;
    }

    const int lane = tid & 63;
    const int wv = (blockIdx.x - GDI_BLOCKS) * 4 + (tid >> 6);
    const int hc = *heavy_cnt;

    const float4* __restrict__ x4 = (const float4*)vx;
    const float4* __restrict__ y4 = (const float4*)vy;
    const float4* __restrict__ z4 = (const float4*)vz;

    for (int item = wv; item < hc; item += HEAVY_WAVES) {
        const int t = heavy[item];
        const bool is_ds = (t >= NHAND);
        const int i_out = is_ds ? (t - NHAND) : t;
        const int q = is_ds ? ds[i_out] : hand_idx[t];
        const float* __restrict__ grow = geodist + (size_t)q * NV;
        const float px = vx[q], py = vy[q], pz = vz[q];
        const float4* __restrict__ g4p = (const float4*)grow;  // 4B-aligned OK

        float best = INFINITY;
        #pragma unroll 4
        for (int j = lane; j < NVEC4; j += 64) {
            const float4 g4 = g4p[j];
            const float4 cx = x4[j];
            const float4 cy = y4[j];
            const float4 cz = z4[j];
            upd(g4.x, cx.x, cy.x, cz.x, px, py, pz, best);
            upd(g4.y, cx.y, cy.y, cz.y, px, py, pz, best);
            upd(g4.z, cx.z, cy.z, cz.z, px, py, pz, best);
            upd(g4.w, cx.w, cy.w, cz.w, px, py, pz, best);
        }
        if (lane < NV - TAIL0) {   // 3 tail candidates
            const int n = TAIL0 + lane;
            upd(grow[n], vx[n], vy[n], vz[n], px, py, pz, best);
        }

        #pragma unroll
        for (int off = 32; off > 0; off >>= 1)
            best = fminf(best, __shfl_down(best, off));

        if (lane == 0) {
            const float d = sqrtf(best + 1e-12f);
            if (is_ds) ds_min[i_out] = d; else hand_min[t] = d;
        }
    }
}

// ---------------------------------------------------------------------------
// K3: finalize (single block). Inside-vertex bitmask in LDS (duplicate-safe
// scatter-max), then all masked means -> scalar loss. gdi via pgdi gather.
// ---------------------------------------------------------------------------
__global__ void finalize_kernel(const float* __restrict__ ds_min,
                                const float* __restrict__ pgdi,
                                const int* __restrict__ ds,
                                const float* __restrict__ hand_min,
                                const float* __restrict__ hw,
                                const int* __restrict__ hand_idx,
                                float* __restrict__ out) {
    __shared__ unsigned int imask[MASK_DW];
    const int tid = threadIdx.x;
    const int nthr = blockDim.x;

    for (int i = tid; i < MASK_DW; i += nthr) imask[i] = 0u;
    __syncthreads();
    for (int i = tid; i < NDS; i += nthr) {
        if (!(ds_min[i] > EXT_THRESH)) {
            const int v = ds[i];
            atomicOr(&imask[v >> 5], 1u << (v & 31));
        }
    }
    __syncthreads();

    float acc[12];
    #pragma unroll
    for (int k = 0; k < 12; ++k) acc[k] = 0.0f;

    for (int i = tid; i < NDS; i += nthr) {
        const float m = ds_min[i];
        const int v = ds[i];
        const bool ins = (imask[v >> 5] >> (v & 31)) & 1u;
        if (!ins) {
            const float w = 1.0f / (5.0f * pgdi[v] + 1.0f);
            acc[0] += A1c * w * tanhf(m / A2c);
            acc[1] += 1.0f;
        } else {
            acc[2] += B1c * tanhf(m / B2c);
            acc[3] += 1.0f;
        }
    }

    for (int h = tid; h < NHAND; h += nthr) {
        const float m = hand_min[h];
        const int v = hand_idx[h];
        const bool ins = (imask[v >> 5] >> (v & 31)) & 1u;
        const float w = -0.1f * hw[h] + 1.0f;
        const float o = w * C1c * tanhf(m / C2c);
        const float ii = D1c * tanhf(m / D2c);
        if (h < NHA) {
            if (!ins) { acc[4] += o;  acc[5] += 1.0f; }
            else      { acc[8] += ii; acc[9] += 1.0f; }
        } else {
            if (!ins) { acc[6]  += o;  acc[7]  += 1.0f; }
            else      { acc[10] += ii; acc[11] += 1.0f; }
        }
    }

    __shared__ float red[16][12];
    const int lane = tid & 63;
    const int wave = tid >> 6;
    #pragma unroll
    for (int k = 0; k < 12; ++k) {
        float v = acc[k];
        #pragma unroll
        for (int off = 32; off > 0; off >>= 1)
            v += __shfl_down(v, off);
        acc[k] = v;
    }
    if (lane == 0) {
        #pragma unroll
        for (int k = 0; k < 12; ++k) red[wave][k] = acc[k];
    }
    __syncthreads();
    if (tid == 0) {
        float t[12];
        const int nw = nthr >> 6;
        #pragma unroll
        for (int k = 0; k < 12; ++k) {
            float s = red[0][k];
            for (int w = 1; w < nw; ++w) s += red[w][k];
            t[k] = s;
        }
        const float contactloss = CONTACT_W * (t[0] / fmaxf(t[1], 1.0f));
        const float insideloss  = INSIDE_W  * (t[2] / fmaxf(t[3], 1.0f));
        const float hand_out = t[4] / fmaxf(t[5], 1.0f) + t[6]  / fmaxf(t[7], 1.0f);
        const float hand_in  = t[8] / fmaxf(t[9], 1.0f) + t[10] / fmaxf(t[11], 1.0f);
        out[0] = contactloss + insideloss + HAND_W * (hand_out + hand_in);
    }
}

extern "C" void kernel_launch(void* const* d_in, const int* in_sizes, int n_in,
                              void* d_out, int out_size, void* d_ws, size_t ws_size,
                              hipStream_t stream) {
    const float* vertices = (const float*)d_in[0];  // [1,NV,3]
    const float* geodist  = (const float*)d_in[1];  // [NV,NV]
    const float* hand_w   = (const float*)d_in[2];  // [NHAND]
    const int*   ds       = (const int*)d_in[3];    // [NDS]
    const int*   hand_idx = (const int*)d_in[4];    // [NHAND]
    const int*   cidx     = (const int*)d_in[5];    // [NCONTACT]
    float* out = (float*)d_out;

    // workspace layout (16B-aligned chunks)
    char* p = (char*)d_ws;
    float* vx = (float*)p;        p += ((NV * 4 + 15) & ~15);
    float* vy = (float*)p;        p += ((NV * 4 + 15) & ~15);
    float* vz = (float*)p;        p += ((NV * 4 + 15) & ~15);
    float* hand_min = (float*)p;  p += ((NHAND * 4 + 15) & ~15);
    float* ds_min = (float*)p;    p += ((NDS * 4 + 15) & ~15);
    float* pgdi = (float*)p;      p += ((NV * 4 + 15) & ~15);
    int* heavy_cnt = (int*)p;     p += 16;
    int* heavy = (int*)p;         p += ((NQ * 4 + 15) & ~15);

    // d_ws poisoned 0xAA before timing -> zero the queue counter every call
    hipMemsetAsync(heavy_cnt, 0, sizeof(int), stream);

    prep_light_kernel<<<K1_BLOCKS, 256, 0, stream>>>(
        vertices, geodist, hand_idx, ds, vx, vy, vz,
        hand_min, ds_min, heavy_cnt, heavy);

    gdi_heavy_kernel<<<K2_BLOCKS, 256, 0, stream>>>(
        geodist, vx, vy, vz, hand_idx, ds, cidx,
        heavy_cnt, heavy, hand_min, ds_min, pgdi);

    finalize_kernel<<<1, 1024, 0, stream>>>(ds_min, pgdi, ds, hand_min,
                                            hand_w, hand_idx, out);
}

// Round 11
// 37.949 us; speedup vs baseline: 2.0513x; 2.0513x over previous
//
#include <hip/hip_runtime.h>
#include <hip/hip_fp16.h>
#include <math.h>

#define NV 10475
#define NDS 2048
#define NHAND 1554
#define NHA 777
#define NCONTACT 300
#define NQ (NHAND + NDS)             // 3602 query rows
#define NVEC4 (NV / 4)               // 2618 float4 per row
#define TAIL0 (NVEC4 * 4)            // 10472
#define MASK_DW ((NV + 31) / 32)     // 328

#define THREADS 512
#define SCAN_BLOCKS ((NQ + 7) / 8)   // 451 blocks * 8 waves = 3608 >= NQ

#define GDI_CHUNKS 25                // 25 chunks * 12 rows = 300 contact rows
#define GDI_ROWS 12
#define GDI_GROUPS ((NV + THREADS - 1) / THREADS)   // 21 col groups of 512
#define GDI_BLOCKS (GDI_CHUNKS * GDI_GROUPS)        // 525
#define MAIN_BLOCKS (SCAN_BLOCKS + GDI_BLOCKS)      // 976

#define GEO_THRESH 0.3f
#define EXT_THRESH 0.02f
#define A1c 0.04f
#define A2c 0.04f
#define B1c 0.07f
#define B2c 0.06f
#define C1c 0.01f
#define C2c 0.01f
#define D1c 0.023f
#define D2c 0.02f
#define CONTACT_W 0.5f
#define INSIDE_W 0.5f
#define HAND_W 1.0f

__device__ __forceinline__ void upd(float g, float cx, float cy, float cz,
                                    float px, float py, float pz, float& best) {
    float dx = px - cx, dy = py - cy, dz = pz - cz;
    float d2 = fmaf(dx, dx, fmaf(dy, dy, dz * dz));
    best = fminf(best, (g < GEO_THRESH) ? INFINITY : d2);
}

// ---------------------------------------------------------------------------
// Prep: fp16-round vertices -> global SoA float arrays (exact half->float).
// ---------------------------------------------------------------------------
__global__ void prep_kernel(const float* __restrict__ verts,
                            float* __restrict__ vx,
                            float* __restrict__ vy,
                            float* __restrict__ vz) {
    const int n = blockIdx.x * 256 + threadIdx.x;
    if (n < NV) {
        vx[n] = __half2float(__float2half(verts[3 * n + 0]));
        vy[n] = __half2float(__float2half(verts[3 * n + 1]));
        vz[n] = __half2float(__float2half(verts[3 * n + 2]));
    }
}

// ---------------------------------------------------------------------------
// Main kernel.
//  Blocks [0, SCAN_BLOCKS): one wave per query. Read diagonal geodist[q][q]:
//   if >= GEO_THRESH the unmasked self-pair (d2 == 0) is the min -> write
//   sqrt(1e-12) immediately (light, ~85%). Else run the full masked float4
//   row scan with coords from L2-resident vx/vy/vz (heavy, ~15%); the self
//   candidate is auto-masked because geodist[q][q] < GEO_THRESH.
//  Blocks [SCAN_BLOCKS, MAIN_BLOCKS): gdi partials. Chunk c of 12 contact
//   rows x col-group g of 512: pgdi[c][v] = min_j geodist[cidx[j], v]
//   (== geodist[v, cidx[j]] by exact symmetry). 12 independent loads in
//   flight per thread, 525 blocks -> fully parallel.
// ---------------------------------------------------------------------------
__global__ void main_kernel(const float* __restrict__ geodist,
                            const float* __restrict__ vx,
                            const float* __restrict__ vy,
                            const float* __restrict__ vz,
                            const int* __restrict__ hand_idx,
                            const int* __restrict__ ds,
                            const int* __restrict__ cidx,
                            float* __restrict__ hand_min,
                            float* __restrict__ ds_min,
                            float* __restrict__ pgdi) {
    const int tid = threadIdx.x;

    if (blockIdx.x >= SCAN_BLOCKS) {
        const int b = blockIdx.x - SCAN_BLOCKS;
        const int g = b % GDI_GROUPS;
        const int c = b / GDI_GROUPS;
        const int v = g * THREADS + tid;
        if (v < NV) {
            const int j0 = c * GDI_ROWS;
            float m = INFINITY;
            #pragma unroll
            for (int j = 0; j < GDI_ROWS; ++j) {
                m = fminf(m, geodist[(size_t)cidx[j0 + j] * NV + v]);
            }
            pgdi[(size_t)c * NV + v] = m;
        }
        return;
    }

    const int lane = tid & 63;
    const int gw = blockIdx.x * (THREADS / 64) + (tid >> 6);
    if (gw >= NQ) return;

    const bool is_ds = (gw >= NHAND);
    const int i_out = is_ds ? (gw - NHAND) : gw;
    const int q = is_ds ? ds[i_out] : hand_idx[gw];

    const float gqq = geodist[(size_t)q * NV + q];   // broadcast load
    if (gqq >= GEO_THRESH) {
        // light: self-pair unmasked, d2 = 0 is the global min
        if (lane == 0) {
            const float d = sqrtf(0.0f + 1e-12f);
            if (is_ds) ds_min[i_out] = d; else hand_min[gw] = d;
        }
        return;
    }

    // heavy: full masked row scan
    const float* __restrict__ grow = geodist + (size_t)q * NV;
    const float px = vx[q], py = vy[q], pz = vz[q];
    const float4* __restrict__ g4p = (const float4*)grow;   // 4B-aligned OK
    const float4* __restrict__ x4 = (const float4*)vx;
    const float4* __restrict__ y4 = (const float4*)vy;
    const float4* __restrict__ z4 = (const float4*)vz;

    float best = INFINITY;
    #pragma unroll 4
    for (int j = lane; j < NVEC4; j += 64) {
        const float4 g4 = g4p[j];
        const float4 cx = x4[j];
        const float4 cy = y4[j];
        const float4 cz = z4[j];
        upd(g4.x, cx.x, cy.x, cz.x, px, py, pz, best);
        upd(g4.y, cx.y, cy.y, cz.y, px, py, pz, best);
        upd(g4.z, cx.z, cy.z, cz.z, px, py, pz, best);
        upd(g4.w, cx.w, cy.w, cz.w, px, py, pz, best);
    }
    if (lane < NV - TAIL0) {   // 3 tail candidates
        const int n = TAIL0 + lane;
        upd(grow[n], vx[n], vy[n], vz[n], px, py, pz, best);
    }

    #pragma unroll
    for (int off = 32; off > 0; off >>= 1)
        best = fminf(best, __shfl_down(best, off));

    if (lane == 0) {
        const float d = sqrtf(best + 1e-12f);
        if (is_ds) ds_min[i_out] = d; else hand_min[gw] = d;
    }
}

// ---------------------------------------------------------------------------
// Finalize: single block. Inside-vertex bitmask in LDS (duplicate-safe
// scatter-max), then all masked means -> scalar loss. gdi = min over the 25
// chunk partials at v = ds[i].
// ---------------------------------------------------------------------------
__global__ void finalize_kernel(const float* __restrict__ ds_min,
                                const float* __restrict__ pgdi,
                                const int* __restrict__ ds,
                                const float* __restrict__ hand_min,
                                const float* __restrict__ hw,
                                const int* __restrict__ hand_idx,
                                float* __restrict__ out) {
    __shared__ unsigned int imask[MASK_DW];
    const int tid = threadIdx.x;
    const int nthr = blockDim.x;

    for (int i = tid; i < MASK_DW; i += nthr) imask[i] = 0u;
    __syncthreads();
    for (int i = tid; i < NDS; i += nthr) {
        if (!(ds_min[i] > EXT_THRESH)) {
            const int v = ds[i];
            atomicOr(&imask[v >> 5], 1u << (v & 31));
        }
    }
    __syncthreads();

    float acc[12];
    #pragma unroll
    for (int k = 0; k < 12; ++k) acc[k] = 0.0f;

    for (int i = tid; i < NDS; i += nthr) {
        const float m = ds_min[i];
        const int v = ds[i];
        const bool ins = (imask[v >> 5] >> (v & 31)) & 1u;
        if (!ins) {
            float gdi = pgdi[v];
            #pragma unroll
            for (int c = 1; c < GDI_CHUNKS; ++c)
                gdi = fminf(gdi, pgdi[(size_t)c * NV + v]);
            const float w = 1.0f / (5.0f * gdi + 1.0f);
            acc[0] += A1c * w * tanhf(m / A2c);
            acc[1] += 1.0f;
        } else {
            acc[2] += B1c * tanhf(m / B2c);
            acc[3] += 1.0f;
        }
    }

    for (int h = tid; h < NHAND; h += nthr) {
        const float m = hand_min[h];
        const int v = hand_idx[h];
        const bool ins = (imask[v >> 5] >> (v & 31)) & 1u;
        const float w = -0.1f * hw[h] + 1.0f;
        const float o = w * C1c * tanhf(m / C2c);
        const float ii = D1c * tanhf(m / D2c);
        if (h < NHA) {
            if (!ins) { acc[4] += o;  acc[5] += 1.0f; }
            else      { acc[8] += ii; acc[9] += 1.0f; }
        } else {
            if (!ins) { acc[6]  += o;  acc[7]  += 1.0f; }
            else      { acc[10] += ii; acc[11] += 1.0f; }
        }
    }

    __shared__ float red[16][12];
    const int lane = tid & 63;
    const int wave = tid >> 6;
    #pragma unroll
    for (int k = 0; k < 12; ++k) {
        float v = acc[k];
        #pragma unroll
        for (int off = 32; off > 0; off >>= 1)
            v += __shfl_down(v, off);
        acc[k] = v;
    }
    if (lane == 0) {
        #pragma unroll
        for (int k = 0; k < 12; ++k) red[wave][k] = acc[k];
    }
    __syncthreads();
    if (tid == 0) {
        float t[12];
        const int nw = nthr >> 6;
        #pragma unroll
        for (int k = 0; k < 12; ++k) {
            float s = red[0][k];
            for (int w = 1; w < nw; ++w) s += red[w][k];
            t[k] = s;
        }
        const float contactloss = CONTACT_W * (t[0] / fmaxf(t[1], 1.0f));
        const float insideloss  = INSIDE_W  * (t[2] / fmaxf(t[3], 1.0f));
        const float hand_out = t[4] / fmaxf(t[5], 1.0f) + t[6]  / fmaxf(t[7], 1.0f);
        const float hand_in  = t[8] / fmaxf(t[9], 1.0f) + t[10] / fmaxf(t[11], 1.0f);
        out[0] = contactloss + insideloss + HAND_W * (hand_out + hand_in);
    }
}

extern "C" void kernel_launch(void* const* d_in, const int* in_sizes, int n_in,
                              void* d_out, int out_size, void* d_ws, size_t ws_size,
                              hipStream_t stream) {
    const float* vertices = (const float*)d_in[0];  // [1,NV,3]
    const float* geodist  = (const float*)d_in[1];  // [NV,NV]
    const float* hand_w   = (const float*)d_in[2];  // [NHAND]
    const int*   ds       = (const int*)d_in[3];    // [NDS]
    const int*   hand_idx = (const int*)d_in[4];    // [NHAND]
    const int*   cidx     = (const int*)d_in[5];    // [NCONTACT]
    float* out = (float*)d_out;

    // workspace layout (16B-aligned chunks)
    char* p = (char*)d_ws;
    float* vx = (float*)p;        p += ((NV * 4 + 15) & ~15);
    float* vy = (float*)p;        p += ((NV * 4 + 15) & ~15);
    float* vz = (float*)p;        p += ((NV * 4 + 15) & ~15);
    float* hand_min = (float*)p;  p += ((NHAND * 4 + 15) & ~15);
    float* ds_min = (float*)p;    p += ((NDS * 4 + 15) & ~15);
    float* pgdi = (float*)p;      p += (((size_t)GDI_CHUNKS * NV * 4 + 15) & ~15);

    prep_kernel<<<41, 256, 0, stream>>>(vertices, vx, vy, vz);

    main_kernel<<<MAIN_BLOCKS, THREADS, 0, stream>>>(
        geodist, vx, vy, vz, hand_idx, ds, cidx, hand_min, ds_min, pgdi);

    finalize_kernel<<<1, 1024, 0, stream>>>(ds_min, pgdi, ds, hand_min,
                                            hand_w, hand_idx, out);
}

// Round 12
// 34.994 us; speedup vs baseline: 2.2245x; 1.0845x over previous
//
#include <hip/hip_runtime.h>
#include <hip/hip_fp16.h>
#include <math.h>

#define NV 10475
#define NDS 2048
#define NHAND 1554
#define NHA 777
#define NCONTACT 300
#define NQ (NHAND + NDS)             // 3602 query rows
#define NVEC4 (NV / 4)               // 2618 float4 per row
#define TAIL0 (NVEC4 * 4)            // 10472
#define MASK_DW ((NV + 31) / 32)     // 328

#define THREADS 512
#define SCAN_BLOCKS ((NQ + 7) / 8)   // 451 blocks * 8 waves = 3608 >= NQ

#define GDI_CHUNKS 25                // 25 chunks * 12 rows = 300 contact rows
#define GDI_ROWS 12
#define GDI_GROUPS ((NV + THREADS - 1) / THREADS)   // 21 col groups of 512
#define GDI_BLOCKS (GDI_CHUNKS * GDI_GROUPS)        // 525
#define MAIN_BLOCKS (SCAN_BLOCKS + GDI_BLOCKS)      // 976

#define GEO_THRESH 0.3f
#define EXT_THRESH 0.02f
#define A1c 0.04f
#define A2c 0.04f
#define B1c 0.07f
#define B2c 0.06f
#define C1c 0.01f
#define C2c 0.01f
#define D1c 0.023f
#define D2c 0.02f
#define CONTACT_W 0.5f
#define INSIDE_W 0.5f
#define HAND_W 1.0f

// fp16 round-trip (RN), identical to the reference's fp16 cast
__device__ __forceinline__ float rnd(float x) {
    return __half2float(__float2half(x));
}

__device__ __forceinline__ void upd(float g, float cx, float cy, float cz,
                                    float px, float py, float pz, float& best) {
    float dx = px - cx, dy = py - cy, dz = pz - cz;
    float d2 = fmaf(dx, dx, fmaf(dy, dy, dz * dz));
    best = fminf(best, (g < GEO_THRESH) ? INFINITY : d2);
}

// ---------------------------------------------------------------------------
// Main kernel (node 1 of 2).
//  Blocks [0, SCAN_BLOCKS): one wave per query. Read diagonal geodist[q][q]:
//   if >= GEO_THRESH the unmasked self-pair (d2 == 0) is the min -> write
//   sqrt(1e-12) immediately (light, ~85%). Else full masked float4 row scan
//   (heavy, ~15%); coords read DIRECTLY from verts (float4 x3 per 4
//   candidates, L2-resident) with in-register fp16 rounding -- no prep pass.
//   Self candidate auto-masked since geodist[q][q] < GEO_THRESH.
//  Blocks [SCAN_BLOCKS, MAIN_BLOCKS): gdi partials. Chunk c (12 contact rows)
//   x col-group g: pgdi[c][v] = min_j geodist[cidx[j], v] (symmetry-exact).
// ---------------------------------------------------------------------------
__global__ __launch_bounds__(THREADS, 4)
void main_kernel(const float* __restrict__ verts,
                 const float* __restrict__ geodist,
                 const int* __restrict__ hand_idx,
                 const int* __restrict__ ds,
                 const int* __restrict__ cidx,
                 float* __restrict__ hand_min,
                 float* __restrict__ ds_min,
                 float* __restrict__ pgdi) {
    const int tid = threadIdx.x;

    if (blockIdx.x >= SCAN_BLOCKS) {
        const int b = blockIdx.x - SCAN_BLOCKS;
        const int g = b % GDI_GROUPS;
        const int c = b / GDI_GROUPS;
        const int v = g * THREADS + tid;
        if (v < NV) {
            const int j0 = c * GDI_ROWS;
            float m = INFINITY;
            #pragma unroll
            for (int j = 0; j < GDI_ROWS; ++j) {
                m = fminf(m, geodist[(size_t)cidx[j0 + j] * NV + v]);
            }
            pgdi[(size_t)c * NV + v] = m;
        }
        return;
    }

    const int lane = tid & 63;
    const int gw = blockIdx.x * (THREADS / 64) + (tid >> 6);
    if (gw >= NQ) return;

    const bool is_ds = (gw >= NHAND);
    const int i_out = is_ds ? (gw - NHAND) : gw;
    const int q = is_ds ? ds[i_out] : hand_idx[gw];

    const float gqq = geodist[(size_t)q * NV + q];   // broadcast load
    if (gqq >= GEO_THRESH) {
        // light: self-pair unmasked, d2 = 0 is the global min
        if (lane == 0) {
            const float d = sqrtf(0.0f + 1e-12f);
            if (is_ds) ds_min[i_out] = d; else hand_min[gw] = d;
        }
        return;
    }

    // heavy: full masked row scan, coords straight from verts
    const float* __restrict__ grow = geodist + (size_t)q * NV;
    const float px = rnd(verts[3 * q + 0]);
    const float py = rnd(verts[3 * q + 1]);
    const float pz = rnd(verts[3 * q + 2]);
    const float4* __restrict__ g4p = (const float4*)grow;   // 4B-aligned OK
    const float4* __restrict__ v4 = (const float4*)verts;   // [NV*3/4] float4

    float best = INFINITY;
    #pragma unroll 4
    for (int j = lane; j < NVEC4; j += 64) {
        const float4 g4 = g4p[j];
        const float4 a = v4[3 * j + 0];   // x0 y0 z0 x1
        const float4 b = v4[3 * j + 1];   // y1 z1 x2 y2
        const float4 c = v4[3 * j + 2];   // z2 x3 y3 z3
        upd(g4.x, rnd(a.x), rnd(a.y), rnd(a.z), px, py, pz, best);
        upd(g4.y, rnd(a.w), rnd(b.x), rnd(b.y), px, py, pz, best);
        upd(g4.z, rnd(b.z), rnd(b.w), rnd(c.x), px, py, pz, best);
        upd(g4.w, rnd(c.y), rnd(c.z), rnd(c.w), px, py, pz, best);
    }
    if (lane < NV - TAIL0) {   // 3 tail candidates
        const int n = TAIL0 + lane;
        upd(grow[n], rnd(verts[3 * n + 0]), rnd(verts[3 * n + 1]),
            rnd(verts[3 * n + 2]), px, py, pz, best);
    }

    #pragma unroll
    for (int off = 32; off > 0; off >>= 1)
        best = fminf(best, __shfl_down(best, off));

    if (lane == 0) {
        const float d = sqrtf(best + 1e-12f);
        if (is_ds) ds_min[i_out] = d; else hand_min[gw] = d;
    }
}

// ---------------------------------------------------------------------------
// Finalize (node 2 of 2): single block. Inside-vertex bitmask in LDS
// (duplicate-safe scatter-max), then all masked means -> scalar loss.
// gdi = min over the 25 chunk partials at v = ds[i].
// ---------------------------------------------------------------------------
__global__ void finalize_kernel(const float* __restrict__ ds_min,
                                const float* __restrict__ pgdi,
                                const int* __restrict__ ds,
                                const float* __restrict__ hand_min,
                                const float* __restrict__ hw,
                                const int* __restrict__ hand_idx,
                                float* __restrict__ out) {
    __shared__ unsigned int imask[MASK_DW];
    const int tid = threadIdx.x;
    const int nthr = blockDim.x;

    for (int i = tid; i < MASK_DW; i += nthr) imask[i] = 0u;
    __syncthreads();
    for (int i = tid; i < NDS; i += nthr) {
        if (!(ds_min[i] > EXT_THRESH)) {
            const int v = ds[i];
            atomicOr(&imask[v >> 5], 1u << (v & 31));
        }
    }
    __syncthreads();

    float acc[12];
    #pragma unroll
    for (int k = 0; k < 12; ++k) acc[k] = 0.0f;

    for (int i = tid; i < NDS; i += nthr) {
        const float m = ds_min[i];
        const int v = ds[i];
        const bool ins = (imask[v >> 5] >> (v & 31)) & 1u;
        if (!ins) {
            float gdi = pgdi[v];
            #pragma unroll
            for (int c = 1; c < GDI_CHUNKS; ++c)
                gdi = fminf(gdi, pgdi[(size_t)c * NV + v]);
            const float w = 1.0f / (5.0f * gdi + 1.0f);
            acc[0] += A1c * w * tanhf(m / A2c);
            acc[1] += 1.0f;
        } else {
            acc[2] += B1c * tanhf(m / B2c);
            acc[3] += 1.0f;
        }
    }

    for (int h = tid; h < NHAND; h += nthr) {
        const float m = hand_min[h];
        const int v = hand_idx[h];
        const bool ins = (imask[v >> 5] >> (v & 31)) & 1u;
        const float w = -0.1f * hw[h] + 1.0f;
        const float o = w * C1c * tanhf(m / C2c);
        const float ii = D1c * tanhf(m / D2c);
        if (h < NHA) {
            if (!ins) { acc[4] += o;  acc[5] += 1.0f; }
            else      { acc[8] += ii; acc[9] += 1.0f; }
        } else {
            if (!ins) { acc[6]  += o;  acc[7]  += 1.0f; }
            else      { acc[10] += ii; acc[11] += 1.0f; }
        }
    }

    __shared__ float red[16][12];
    const int lane = tid & 63;
    const int wave = tid >> 6;
    #pragma unroll
    for (int k = 0; k < 12; ++k) {
        float v = acc[k];
        #pragma unroll
        for (int off = 32; off > 0; off >>= 1)
            v += __shfl_down(v, off);
        acc[k] = v;
    }
    if (lane == 0) {
        #pragma unroll
        for (int k = 0; k < 12; ++k) red[wave][k] = acc[k];
    }
    __syncthreads();
    if (tid == 0) {
        float t[12];
        const int nw = nthr >> 6;
        #pragma unroll
        for (int k = 0; k < 12; ++k) {
            float s = red[0][k];
            for (int w = 1; w < nw; ++w) s += red[w][k];
            t[k] = s;
        }
        const float contactloss = CONTACT_W * (t[0] / fmaxf(t[1], 1.0f));
        const float insideloss  = INSIDE_W  * (t[2] / fmaxf(t[3], 1.0f));
        const float hand_out = t[4] / fmaxf(t[5], 1.0f) + t[6]  / fmaxf(t[7], 1.0f);
        const float hand_in  = t[8] / fmaxf(t[9], 1.0f) + t[10] / fmaxf(t[11], 1.0f);
        out[0] = contactloss + insideloss + HAND_W * (hand_out + hand_in);
    }
}

extern "C" void kernel_launch(void* const* d_in, const int* in_sizes, int n_in,
                              void* d_out, int out_size, void* d_ws, size_t ws_size,
                              hipStream_t stream) {
    const float* vertices = (const float*)d_in[0];  // [1,NV,3]
    const float* geodist  = (const float*)d_in[1];  // [NV,NV]
    const float* hand_w   = (const float*)d_in[2];  // [NHAND]
    const int*   ds       = (const int*)d_in[3];    // [NDS]
    const int*   hand_idx = (const int*)d_in[4];    // [NHAND]
    const int*   cidx     = (const int*)d_in[5];    // [NCONTACT]
    float* out = (float*)d_out;

    // workspace layout (16B-aligned chunks)
    char* p = (char*)d_ws;
    float* hand_min = (float*)p;  p += ((NHAND * 4 + 15) & ~15);
    float* ds_min = (float*)p;    p += ((NDS * 4 + 15) & ~15);
    float* pgdi = (float*)p;      p += (((size_t)GDI_CHUNKS * NV * 4 + 15) & ~15);

    main_kernel<<<MAIN_BLOCKS, THREADS, 0, stream>>>(
        vertices, geodist, hand_idx, ds, cidx, hand_min, ds_min, pgdi);

    finalize_kernel<<<1, 1024, 0, stream>>>(ds_min, pgdi, ds, hand_min,
                                            hand_w, hand_idx, out);
}